// Round 1
// baseline (264.956 us; speedup 1.0000x reference)
//
#include <hip/hip_runtime.h>

#define AS1(p) ((const __attribute__((address_space(1))) void*)(p))
#define AS3(p) ((__attribute__((address_space(3))) void*)(p))

typedef __attribute__((ext_vector_type(8))) short bf16x8;
typedef __attribute__((ext_vector_type(4))) float f32x4;

static constexpr int kBatch = 8;
static constexpr int kSeq = 1024;
static constexpr int kD = 1024;
static constexpr int kH = 16;
static constexpr int kHD = 64;
static constexpr int kRows = kBatch * kSeq;   // 8192
static constexpr int kQKVCols = 3 * kD;       // 3072
#define ATT_SCALE 0.125f

__device__ __forceinline__ unsigned short f2bf(float f) {
  union { float f; unsigned int u; } a; a.f = f;
  unsigned int r = a.u + 0x7fffu + ((a.u >> 16) & 1u);
  return (unsigned short)(r >> 16);
}

// ---------------- f32 -> bf16 elementwise convert (vectorized) ----------------
__global__ void cvt_bf16_kernel(const float* __restrict__ in,
                                unsigned short* __restrict__ out, int n4) {
  int i = blockIdx.x * blockDim.x + threadIdx.x;
  int stride = gridDim.x * blockDim.x;
  for (; i < n4; i += stride) {
    float4 v = reinterpret_cast<const float4*>(in)[i];
    ushort4 o;
    o.x = f2bf(v.x); o.y = f2bf(v.y); o.z = f2bf(v.z); o.w = f2bf(v.w);
    reinterpret_cast<ushort4*>(out)[i] = o;
  }
}

// ---------------- transpose + convert: W (rows x cols) -> Wt (cols x rows) bf16
__global__ void transpose_cvt_kernel(const float* __restrict__ W,
                                     unsigned short* __restrict__ Wt,
                                     int rows, int cols) {
  __shared__ float tile[32][33];
  int c0 = blockIdx.x * 32, r0 = blockIdx.y * 32;
  int tx = threadIdx.x, ty = threadIdx.y;
#pragma unroll
  for (int i = 0; i < 32; i += 8)
    tile[ty + i][tx] = W[(size_t)(r0 + ty + i) * cols + (c0 + tx)];
  __syncthreads();
#pragma unroll
  for (int i = 0; i < 32; i += 8)
    Wt[(size_t)(c0 + ty + i) * rows + (r0 + tx)] = f2bf(tile[tx][ty + i]);
}

// ---------------- bf16 GEMM: C = A(MxK) * Bt(NxK)^T + bias, 128x128 tile -----
template <bool OUT_BF16>
__global__ __launch_bounds__(256) void gemm_bt_kernel(
    const unsigned short* __restrict__ A,   // M x K, bf16 bits
    const unsigned short* __restrict__ Bt,  // N x K, bf16 bits (B transposed)
    const float* __restrict__ bias,         // N
    void* __restrict__ Cout, int M, int Nn, int K) {
  constexpr int BK = 64;
  __shared__ alignas(16) unsigned short As[128 * BK];
  __shared__ alignas(16) unsigned short Bs[128 * BK];
  const int t = threadIdx.x;
  const int lane = t & 63;
  const int w = t >> 6;
  const int wr = w >> 1, wc = w & 1;
  const int l15 = lane & 15, lhi = lane >> 4;
  const int row0 = blockIdx.y * 128;
  const int col0 = blockIdx.x * 128;

  f32x4 acc[4][4] = {};
  const int ldsb = (t & ~63) * 16;  // wave-uniform LDS byte base within a round

  for (int k0 = 0; k0 < K; k0 += BK) {
    __syncthreads();
#pragma unroll
    for (int r = 0; r < 4; ++r) {
      int c = r * 256 + t;
      int arow = c >> 3;
      int ccol = ((c & 7) ^ (arow & 7)) * 8;  // pre-swizzled global source
      const unsigned short* ga = A + (size_t)(row0 + arow) * K + (k0 + ccol);
      const unsigned short* gb = Bt + (size_t)(col0 + arow) * K + (k0 + ccol);
      char* la = (char*)As + r * 4096 + ldsb;
      char* lb = (char*)Bs + r * 4096 + ldsb;
      __builtin_amdgcn_global_load_lds(AS1(ga), AS3(la), 16, 0, 0);
      __builtin_amdgcn_global_load_lds(AS1(gb), AS3(lb), 16, 0, 0);
    }
    __syncthreads();
#pragma unroll
    for (int kk = 0; kk < 2; ++kk) {
      bf16x8 af[4], bfr[4];
#pragma unroll
      for (int mi = 0; mi < 4; ++mi) {
        int rowa = wr * 64 + mi * 16 + l15;
        int chunk = (kk * 4 + lhi) ^ (rowa & 7);  // swizzled read
        af[mi] = *reinterpret_cast<const bf16x8*>((const char*)As + rowa * 128 + chunk * 16);
      }
#pragma unroll
      for (int ni = 0; ni < 4; ++ni) {
        int rowb = wc * 64 + ni * 16 + l15;
        int chunk = (kk * 4 + lhi) ^ (rowb & 7);
        bfr[ni] = *reinterpret_cast<const bf16x8*>((const char*)Bs + rowb * 128 + chunk * 16);
      }
#pragma unroll
      for (int mi = 0; mi < 4; ++mi)
#pragma unroll
        for (int ni = 0; ni < 4; ++ni)
          acc[mi][ni] = __builtin_amdgcn_mfma_f32_16x16x32_bf16(af[mi], bfr[ni], acc[mi][ni], 0, 0, 0);
    }
  }
#pragma unroll
  for (int mi = 0; mi < 4; ++mi) {
    int rbase = row0 + wr * 64 + mi * 16 + lhi * 4;
#pragma unroll
    for (int ni = 0; ni < 4; ++ni) {
      int col = col0 + wc * 64 + ni * 16 + l15;
      float bv = bias[col];
#pragma unroll
      for (int j = 0; j < 4; ++j) {
        float v = acc[mi][ni][j] + bv;
        if (OUT_BF16)
          ((unsigned short*)Cout)[(size_t)(rbase + j) * Nn + col] = f2bf(v);
        else
          ((float*)Cout)[(size_t)(rbase + j) * Nn + col] = v;
      }
    }
  }
}

// ---------------- fused flash attention: per (b,h), 64 Q rows per block ------
__global__ __launch_bounds__(256) void attn_kernel(
    const unsigned short* __restrict__ qkv,  // 8192 x 3072 bf16 bits
    unsigned short* __restrict__ ctx) {      // 8192 x 1024 bf16 bits
  __shared__ alignas(16) unsigned short Ks[64 * 64];  // [kk][d]  swizzled
  __shared__ alignas(16) unsigned short Vt[64 * 64];  // [d][kk]  swizzled
  __shared__ alignas(16) unsigned short Ps[64 * 64];  // [q][kk]  swizzled
  const int qt = blockIdx.x;   // 0..15
  const int bh = blockIdx.y;   // 0..127
  const int b = bh >> 4, h = bh & 15;
  const int t = threadIdx.x, lane = t & 63, w = t >> 6;
  const int l15 = lane & 15, lhi = lane >> 4;

  const unsigned short* Qb = qkv + (size_t)b * kSeq * kQKVCols + h * kHD;
  const unsigned short* Kb = Qb + kD;
  const unsigned short* Vb = Qb + 2 * kD;

  bf16x8 qf[2];
  {
    int qrow = qt * 64 + w * 16 + l15;
    const unsigned short* qp = Qb + (size_t)qrow * kQKVCols + lhi * 8;
    qf[0] = *reinterpret_cast<const bf16x8*>(qp);
    qf[1] = *reinterpret_cast<const bf16x8*>(qp + 32);
  }

  f32x4 oacc[4] = {};
  float mrun[4], lrun[4];
#pragma unroll
  for (int j = 0; j < 4; ++j) { mrun[j] = -1e30f; lrun[j] = 0.f; }

  for (int kt = 0; kt < 16; ++kt) {
    __syncthreads();
    // stage K row-major and V transposed, both XOR-swizzled
#pragma unroll
    for (int r = 0; r < 2; ++r) {
      int c = r * 256 + t;
      int krow = c >> 3;
      int c8 = c & 7;
      const size_t goff = (size_t)(kt * 64 + krow) * kQKVCols + c8 * 8;
      uint4 kvv = *reinterpret_cast<const uint4*>(Kb + goff);
      *reinterpret_cast<uint4*>((char*)Ks + krow * 128 + ((c8 ^ (krow & 7)) * 16)) = kvv;
      uint4 vvv = *reinterpret_cast<const uint4*>(Vb + goff);
      unsigned short vtmp[8];
      *reinterpret_cast<uint4*>(vtmp) = vvv;
#pragma unroll
      for (int j = 0; j < 8; ++j) {
        int dd = c8 * 8 + j;
        int chunk = (krow >> 3) ^ (dd & 7);
        Vt[dd * 64 + chunk * 8 + (krow & 7)] = vtmp[j];
      }
    }
    __syncthreads();

    // S = Q K^T * scale   (per wave: 16 q-rows x 64 k-cols)
    f32x4 s[4];
#pragma unroll
    for (int n0 = 0; n0 < 4; ++n0) {
      int krow = n0 * 16 + l15;
      bf16x8 kf0 = *reinterpret_cast<const bf16x8*>((const char*)Ks + krow * 128 + ((lhi ^ (krow & 7)) * 16));
      bf16x8 kf1 = *reinterpret_cast<const bf16x8*>((const char*)Ks + krow * 128 + (((4 + lhi) ^ (krow & 7)) * 16));
      f32x4 z = {};
      z = __builtin_amdgcn_mfma_f32_16x16x32_bf16(qf[0], kf0, z, 0, 0, 0);
      z = __builtin_amdgcn_mfma_f32_16x16x32_bf16(qf[1], kf1, z, 0, 0, 0);
      s[n0] = z * ATT_SCALE;
    }

    // online softmax (rows live on 16-lane groups; j indexes 4 rows per group)
    float tmax[4];
#pragma unroll
    for (int j = 0; j < 4; ++j)
      tmax[j] = fmaxf(fmaxf(s[0][j], s[1][j]), fmaxf(s[2][j], s[3][j]));
#pragma unroll
    for (int mset = 8; mset >= 1; mset >>= 1)
#pragma unroll
      for (int j = 0; j < 4; ++j)
        tmax[j] = fmaxf(tmax[j], __shfl_xor(tmax[j], mset, 64));
    float corr[4], tsum[4];
#pragma unroll
    for (int j = 0; j < 4; ++j) {
      float mnew = fmaxf(mrun[j], tmax[j]);
      corr[j] = __expf(mrun[j] - mnew);
      mrun[j] = mnew;
      tsum[j] = 0.f;
    }
#pragma unroll
    for (int n0 = 0; n0 < 4; ++n0)
#pragma unroll
      for (int j = 0; j < 4; ++j) {
        float p = __expf(s[n0][j] - mrun[j]);
        s[n0][j] = p;
        tsum[j] += p;
      }
#pragma unroll
    for (int mset = 8; mset >= 1; mset >>= 1)
#pragma unroll
      for (int j = 0; j < 4; ++j)
        tsum[j] += __shfl_xor(tsum[j], mset, 64);
#pragma unroll
    for (int j = 0; j < 4; ++j)
      lrun[j] = lrun[j] * corr[j] + tsum[j];
#pragma unroll
    for (int d0 = 0; d0 < 4; ++d0)
#pragma unroll
      for (int j = 0; j < 4; ++j)
        oacc[d0][j] *= corr[j];

    // P -> LDS (bf16, swizzled); each wave owns rows [w*16, w*16+16)
#pragma unroll
    for (int n0 = 0; n0 < 4; ++n0)
#pragma unroll
      for (int j = 0; j < 4; ++j) {
        int prow = w * 16 + lhi * 4 + j;
        int pcol = n0 * 16 + l15;
        Ps[prow * 64 + (((pcol >> 3) ^ (prow & 7)) * 8) + (pcol & 7)] = f2bf(s[n0][j]);
      }

    // O += P V
#pragma unroll
    for (int d0 = 0; d0 < 4; ++d0) {
      int vrow = d0 * 16 + l15;
      int prow = w * 16 + l15;
#pragma unroll
      for (int c = 0; c < 2; ++c) {
        bf16x8 pf = *reinterpret_cast<const bf16x8*>((const char*)Ps + prow * 128 + (((c * 4 + lhi) ^ (prow & 7)) * 16));
        bf16x8 vf = *reinterpret_cast<const bf16x8*>((const char*)Vt + vrow * 128 + (((c * 4 + lhi) ^ (vrow & 7)) * 16));
        oacc[d0] = __builtin_amdgcn_mfma_f32_16x16x32_bf16(pf, vf, oacc[d0], 0, 0, 0);
      }
    }
  }

  // epilogue: O /= l, store bf16 context in (B,N,H*hd) layout
#pragma unroll
  for (int d0 = 0; d0 < 4; ++d0) {
    int col = h * kHD + d0 * 16 + l15;
#pragma unroll
    for (int j = 0; j < 4; ++j) {
      int qrow = qt * 64 + w * 16 + lhi * 4 + j;
      float v = oacc[d0][j] / lrun[j];
      ctx[(size_t)(b * kSeq + qrow) * kD + col] = f2bf(v);
    }
  }
}

extern "C" void kernel_launch(void* const* d_in, const int* in_sizes, int n_in,
                              void* d_out, int out_size, void* d_ws, size_t ws_size,
                              hipStream_t stream) {
  const float* x     = (const float*)d_in[0];  // 8x1024x1024
  const float* Wqkv  = (const float*)d_in[1];  // 1024x3072
  const float* bqkv  = (const float*)d_in[2];  // 3072
  const float* Wproj = (const float*)d_in[3];  // 1024x1024
  const float* bproj = (const float*)d_in[4];  // 1024
  float* out = (float*)d_out;

  char* ws = (char*)d_ws;
  size_t oXbf   = 0;
  size_t oWqkvT = oXbf   + (size_t)kRows * kD * 2;       // 16 MB
  size_t oWpT   = oWqkvT + (size_t)kQKVCols * kD * 2;    // +6 MB
  size_t oQKV   = oWpT   + (size_t)kD * kD * 2;          // +2 MB
  size_t oCTX   = oQKV   + (size_t)kRows * kQKVCols * 2; // +48 MB
  size_t total  = oCTX   + (size_t)kRows * kD * 2;       // +16 MB = ~88 MB
  if (ws_size < total) return;

  unsigned short* Xbf   = (unsigned short*)(ws + oXbf);
  unsigned short* WqkvT = (unsigned short*)(ws + oWqkvT);
  unsigned short* WpT   = (unsigned short*)(ws + oWpT);
  unsigned short* QKV   = (unsigned short*)(ws + oQKV);
  unsigned short* CTX   = (unsigned short*)(ws + oCTX);

  cvt_bf16_kernel<<<2048, 256, 0, stream>>>(x, Xbf, kRows * kD / 4);
  transpose_cvt_kernel<<<dim3(kQKVCols / 32, kD / 32), dim3(32, 8), 0, stream>>>(Wqkv, WqkvT, kD, kQKVCols);
  transpose_cvt_kernel<<<dim3(kD / 32, kD / 32), dim3(32, 8), 0, stream>>>(Wproj, WpT, kD, kD);
  gemm_bt_kernel<true><<<dim3(kQKVCols / 128, kRows / 128), 256, 0, stream>>>(
      Xbf, WqkvT, bqkv, QKV, kRows, kQKVCols, kD);
  attn_kernel<<<dim3(16, 128), 256, 0, stream>>>(QKV, CTX);
  gemm_bt_kernel<false><<<dim3(kD / 128, kRows / 128), 256, 0, stream>>>(
      CTX, WpT, bproj, out, kRows, kD, kD);
}

// Round 2
// 189.515 us; speedup vs baseline: 1.3981x; 1.3981x over previous
//
#include <hip/hip_runtime.h>

#define AS1(p) ((const __attribute__((address_space(1))) void*)(p))
#define AS3(p) ((__attribute__((address_space(3))) void*)(p))

typedef __attribute__((ext_vector_type(8))) short bf16x8;
typedef __attribute__((ext_vector_type(4))) short bf16x4;
typedef __attribute__((ext_vector_type(4))) float f32x4;

static constexpr int kBatch = 8;
static constexpr int kSeq = 1024;
static constexpr int kD = 1024;
static constexpr int kH = 16;
static constexpr int kHD = 64;
static constexpr int kRows = kBatch * kSeq;   // 8192
static constexpr int kQKVCols = 3 * kD;       // 3072

__device__ __forceinline__ unsigned short f2bf(float f) {
  union { float f; unsigned int u; } a; a.f = f;
  unsigned int r = a.u + 0x7fffu + ((a.u >> 16) & 1u);
  return (unsigned short)(r >> 16);
}

// ---------------- f32 -> bf16 elementwise convert (vectorized) ----------------
__global__ void cvt_bf16_kernel(const float* __restrict__ in,
                                unsigned short* __restrict__ out, int n4) {
  int i = blockIdx.x * blockDim.x + threadIdx.x;
  int stride = gridDim.x * blockDim.x;
  for (; i < n4; i += stride) {
    float4 v = reinterpret_cast<const float4*>(in)[i];
    ushort4 o;
    o.x = f2bf(v.x); o.y = f2bf(v.y); o.z = f2bf(v.z); o.w = f2bf(v.w);
    reinterpret_cast<ushort4*>(out)[i] = o;
  }
}

// ---------------- transpose + convert: W (rows x cols) -> Wt (cols x rows) bf16
__global__ void transpose_cvt_kernel(const float* __restrict__ W,
                                     unsigned short* __restrict__ Wt,
                                     int rows, int cols) {
  __shared__ float tile[32][33];
  int c0 = blockIdx.x * 32, r0 = blockIdx.y * 32;
  int tx = threadIdx.x, ty = threadIdx.y;
#pragma unroll
  for (int i = 0; i < 32; i += 8)
    tile[ty + i][tx] = W[(size_t)(r0 + ty + i) * cols + (c0 + tx)];
  __syncthreads();
#pragma unroll
  for (int i = 0; i < 32; i += 8)
    Wt[(size_t)(c0 + ty + i) * rows + (r0 + tx)] = f2bf(tile[tx][ty + i]);
}

// ---------------- V transpose: QKV -> Vt[bh][d][n] (bf16) --------------------
__global__ __launch_bounds__(256) void vtrans_kernel(
    const unsigned short* __restrict__ qkv, unsigned short* __restrict__ Vt) {
  __shared__ alignas(16) unsigned short tile[64][72];  // pad: stride 144B
  const int nt = blockIdx.x, bh = blockIdx.y;
  const int b = bh >> 4, h = bh & 15;
  const unsigned short* Vb = qkv + (size_t)b * kSeq * kQKVCols + 2 * kD + h * kHD;
  const int t = threadIdx.x;
#pragma unroll
  for (int r = 0; r < 2; ++r) {
    const int c = r * 256 + t;
    const int n = c >> 3, d8 = c & 7;
    uint4 v = *reinterpret_cast<const uint4*>(Vb + (size_t)(nt * 64 + n) * kQKVCols + d8 * 8);
    *reinterpret_cast<uint4*>(&tile[n][d8 * 8]) = v;
  }
  __syncthreads();
#pragma unroll
  for (int r = 0; r < 2; ++r) {
    const int c = r * 256 + t;
    const int d = c >> 3, n8 = c & 7;
    unsigned short w8[8];
#pragma unroll
    for (int j = 0; j < 8; ++j) w8[j] = tile[n8 * 8 + j][d];
    *reinterpret_cast<uint4*>(Vt + (size_t)bh * kHD * kSeq + (size_t)d * kSeq + nt * 64 + n8 * 8) =
        *reinterpret_cast<uint4*>(w8);
  }
}

// ---------------- bf16 GEMM: C = A(MxK) * Bt(NxK)^T + bias, 128x128 tile -----
template <bool OUT_BF16>
__global__ __launch_bounds__(256) void gemm_bt_kernel(
    const unsigned short* __restrict__ A,   // M x K, bf16 bits
    const unsigned short* __restrict__ Bt,  // N x K, bf16 bits (B transposed)
    const float* __restrict__ bias,         // N
    void* __restrict__ Cout, int M, int Nn, int K) {
  constexpr int BK = 64;
  __shared__ alignas(16) unsigned short As[128 * BK];
  __shared__ alignas(16) unsigned short Bs[128 * BK];
  const int t = threadIdx.x;
  const int lane = t & 63;
  const int w = t >> 6;
  const int wr = w >> 1, wc = w & 1;
  const int l15 = lane & 15, lhi = lane >> 4;
  // XCD-aware bijective swizzle (grid sizes are multiples of 8)
  const int nwg = gridDim.x * gridDim.y;
  const int lin = blockIdx.y * gridDim.x + blockIdx.x;
  const int swz = (lin & 7) * (nwg >> 3) + (lin >> 3);
  const int row0 = (swz / gridDim.x) * 128;
  const int col0 = (swz % gridDim.x) * 128;

  f32x4 acc[4][4] = {};
  const int ldsb = (t & ~63) * 16;  // wave-uniform LDS byte base within a round

  for (int k0 = 0; k0 < K; k0 += BK) {
    __syncthreads();
#pragma unroll
    for (int r = 0; r < 4; ++r) {
      int c = r * 256 + t;
      int arow = c >> 3;
      int ccol = ((c & 7) ^ (arow & 7)) * 8;  // pre-swizzled global source
      const unsigned short* ga = A + (size_t)(row0 + arow) * K + (k0 + ccol);
      const unsigned short* gb = Bt + (size_t)(col0 + arow) * K + (k0 + ccol);
      char* la = (char*)As + r * 4096 + ldsb;
      char* lb = (char*)Bs + r * 4096 + ldsb;
      __builtin_amdgcn_global_load_lds(AS1(ga), AS3(la), 16, 0, 0);
      __builtin_amdgcn_global_load_lds(AS1(gb), AS3(lb), 16, 0, 0);
    }
    __syncthreads();
#pragma unroll
    for (int kk = 0; kk < 2; ++kk) {
      bf16x8 af[4], bfr[4];
#pragma unroll
      for (int mi = 0; mi < 4; ++mi) {
        int rowa = wr * 64 + mi * 16 + l15;
        int chunk = (kk * 4 + lhi) ^ (rowa & 7);  // swizzled read
        af[mi] = *reinterpret_cast<const bf16x8*>((const char*)As + rowa * 128 + chunk * 16);
      }
#pragma unroll
      for (int ni = 0; ni < 4; ++ni) {
        int rowb = wc * 64 + ni * 16 + l15;
        int chunk = (kk * 4 + lhi) ^ (rowb & 7);
        bfr[ni] = *reinterpret_cast<const bf16x8*>((const char*)Bs + rowb * 128 + chunk * 16);
      }
#pragma unroll
      for (int mi = 0; mi < 4; ++mi)
#pragma unroll
        for (int ni = 0; ni < 4; ++ni)
          acc[mi][ni] = __builtin_amdgcn_mfma_f32_16x16x32_bf16(af[mi], bfr[ni], acc[mi][ni], 0, 0, 0);
    }
  }
#pragma unroll
  for (int mi = 0; mi < 4; ++mi) {
    int rbase = row0 + wr * 64 + mi * 16 + lhi * 4;
#pragma unroll
    for (int ni = 0; ni < 4; ++ni) {
      int col = col0 + wc * 64 + ni * 16 + l15;
      float bv = bias[col];
#pragma unroll
      for (int j = 0; j < 4; ++j) {
        float v = acc[mi][ni][j] + bv;
        if (OUT_BF16)
          ((unsigned short*)Cout)[(size_t)(rbase + j) * Nn + col] = f2bf(v);
        else
          ((float*)Cout)[(size_t)(rbase + j) * Nn + col] = v;
      }
    }
  }
}

// ---------------- fused flash attention (swapped QK^T, register P) -----------
// block = 4 waves; wave owns 16 q rows; KBLK = 64; K and Vt staged via
// global_load_lds with pre-swizzled source + swizzled reads (rule #21).
__global__ __launch_bounds__(256) void attn_kernel(
    const unsigned short* __restrict__ qkv,  // 8192 x 3072 bf16 bits
    const unsigned short* __restrict__ Vt,   // [128][64][1024] bf16 bits
    unsigned short* __restrict__ ctx) {      // 8192 x 1024 bf16 bits
  __shared__ alignas(16) unsigned short Ks[64 * 64];  // [n][d] swizzled
  __shared__ alignas(16) unsigned short Vs[64 * 64];  // [d][n] swizzled
  // XCD swizzle: keep all 16 q-tiles of one (b,h) on one XCD for K/V L2 reuse
  const int lin = blockIdx.x;                  // 2048
  const int swz = (lin & 7) * 256 + (lin >> 3);
  const int qt = swz & 15;
  const int bh = swz >> 4;
  const int b = bh >> 4, h = bh & 15;
  const int t = threadIdx.x, lane = t & 63, w = t >> 6;
  const int l15 = lane & 15, lhi = lane >> 4;

  const unsigned short* Qb = qkv + (size_t)b * kSeq * kQKVCols + h * kHD;
  const unsigned short* Kb = Qb + kD;
  const unsigned short* Vtb = Vt + (size_t)bh * kHD * kSeq;

  // Q fragment (B-operand of S^T mfma): col=q=l15, k=d=lhi*8+j (+32)
  bf16x8 qf0, qf1;
  {
    const int qrow = qt * 64 + w * 16 + l15;
    const unsigned short* qp = Qb + (size_t)qrow * kQKVCols + lhi * 8;
    qf0 = *reinterpret_cast<const bf16x8*>(qp);
    qf1 = *reinterpret_cast<const bf16x8*>(qp + 32);
  }

  f32x4 oacc[4] = {};
  float mrun = -1e30f, lrun = 0.f;
  constexpr float kSc = 0.125f * 1.44269504f;  // head-scale * log2(e)

  for (int kt = 0; kt < 16; ++kt) {
    __syncthreads();
#pragma unroll
    for (int r = 0; r < 2; ++r) {
      const int c = r * 256 + t;
      const int row = c >> 3;
      const int sc = ((c & 7) ^ (row & 7)) * 8;  // pre-swizzled source chunk
      const unsigned short* gk = Kb + (size_t)(kt * 64 + row) * kQKVCols + sc;
      const unsigned short* gv = Vtb + (size_t)row * kSeq + kt * 64 + sc;
      char* lk = (char*)Ks + r * 4096 + (t & ~63) * 16;
      char* lv = (char*)Vs + r * 4096 + (t & ~63) * 16;
      __builtin_amdgcn_global_load_lds(AS1(gk), AS3(lk), 16, 0, 0);
      __builtin_amdgcn_global_load_lds(AS1(gv), AS3(lv), 16, 0, 0);
    }
    __syncthreads();

    // S^T = K·Q^T (rows n, cols q), in log2 domain
    f32x4 s[4];
#pragma unroll
    for (int n0 = 0; n0 < 4; ++n0) {
      const int kr = n0 * 16 + l15;
      bf16x8 kf0 = *reinterpret_cast<const bf16x8*>((const char*)Ks + kr * 128 + ((lhi ^ (kr & 7)) * 16));
      bf16x8 kf1 = *reinterpret_cast<const bf16x8*>((const char*)Ks + kr * 128 + (((4 + lhi) ^ (kr & 7)) * 16));
      f32x4 z = {};
      z = __builtin_amdgcn_mfma_f32_16x16x32_bf16(kf0, qf0, z, 0, 0, 0);
      z = __builtin_amdgcn_mfma_f32_16x16x32_bf16(kf1, qf1, z, 0, 0, 0);
      s[n0] = z * kSc;
    }

    // online softmax over n for q = l15 (lane holds 16 of 64 n-values)
    float tm = s[0][0];
#pragma unroll
    for (int n0 = 0; n0 < 4; ++n0)
#pragma unroll
      for (int j = 0; j < 4; ++j) tm = fmaxf(tm, s[n0][j]);
    tm = fmaxf(tm, __shfl_xor(tm, 16, 64));
    tm = fmaxf(tm, __shfl_xor(tm, 32, 64));
    const float mnew = fmaxf(mrun, tm);
    const float corr = __builtin_amdgcn_exp2f(mrun - mnew);
    mrun = mnew;

    float ps = 0.f;
    bf16x4 pa[4];
#pragma unroll
    for (int n0 = 0; n0 < 4; ++n0) {
      float p0 = __builtin_amdgcn_exp2f(s[n0][0] - mnew);
      float p1 = __builtin_amdgcn_exp2f(s[n0][1] - mnew);
      float p2 = __builtin_amdgcn_exp2f(s[n0][2] - mnew);
      float p3 = __builtin_amdgcn_exp2f(s[n0][3] - mnew);
      ps += (p0 + p1) + (p2 + p3);
      unsigned lo, hi;
      asm("v_cvt_pk_bf16_f32 %0, %1, %2" : "=v"(lo) : "v"(p0), "v"(p1));
      asm("v_cvt_pk_bf16_f32 %0, %1, %2" : "=v"(hi) : "v"(p2), "v"(p3));
      union { unsigned u[2]; bf16x4 v; } pk;
      pk.u[0] = lo; pk.u[1] = hi;
      pa[n0] = pk.v;  // A-frag of 16x16x16: row=q=l15, k=lhi*4+j  == C/D layout
    }
    ps += __shfl_xor(ps, 16, 64);
    ps += __shfl_xor(ps, 32, 64);
    lrun = lrun * corr + ps;

    // rescale O: C/D rows are q = lhi*4+j -> fetch that q's corr from lane q
    float cb[4];
#pragma unroll
    for (int j = 0; j < 4; ++j) cb[j] = __shfl(corr, lhi * 4 + j, 64);
#pragma unroll
    for (int d0 = 0; d0 < 4; ++d0)
#pragma unroll
      for (int j = 0; j < 4; ++j) oacc[d0][j] *= cb[j];

    // O += P · Vt^T via 16x16x16 mfma (A = P in regs, B from swizzled LDS)
#pragma unroll
    for (int d0 = 0; d0 < 4; ++d0) {
      const int dr = d0 * 16 + l15;
#pragma unroll
      for (int n0 = 0; n0 < 4; ++n0) {
        const int ch = (n0 * 2 + (lhi >> 1)) ^ (dr & 7);
        bf16x4 vf = *reinterpret_cast<const bf16x4*>(
            (const char*)Vs + dr * 128 + ch * 16 + (lhi & 1) * 8);
        asm("v_mfma_f32_16x16x16_bf16 %0, %1, %2, %0"
            : "+v"(oacc[d0]) : "v"(pa[n0]), "v"(vf));
      }
    }
  }

  // epilogue: O /= l (broadcast l to C/D row mapping), store bf16 context
  float lb[4];
#pragma unroll
  for (int j = 0; j < 4; ++j) lb[j] = __shfl(lrun, lhi * 4 + j, 64);
#pragma unroll
  for (int d0 = 0; d0 < 4; ++d0) {
    const int col = h * kHD + d0 * 16 + l15;
#pragma unroll
    for (int j = 0; j < 4; ++j) {
      const int qrow = qt * 64 + w * 16 + lhi * 4 + j;
      ctx[(size_t)(b * kSeq + qrow) * kD + col] = f2bf(oacc[d0][j] / lb[j]);
    }
  }
}

extern "C" void kernel_launch(void* const* d_in, const int* in_sizes, int n_in,
                              void* d_out, int out_size, void* d_ws, size_t ws_size,
                              hipStream_t stream) {
  const float* x     = (const float*)d_in[0];  // 8x1024x1024
  const float* Wqkv  = (const float*)d_in[1];  // 1024x3072
  const float* bqkv  = (const float*)d_in[2];  // 3072
  const float* Wproj = (const float*)d_in[3];  // 1024x1024
  const float* bproj = (const float*)d_in[4];  // 1024
  float* out = (float*)d_out;

  char* ws = (char*)d_ws;
  size_t oXbf   = 0;                                     // 16 MB (aliased by Vt)
  size_t oWqkvT = oXbf   + (size_t)kRows * kD * 2;       // +16 MB
  size_t oWpT   = oWqkvT + (size_t)kQKVCols * kD * 2;    // +6 MB
  size_t oQKV   = oWpT   + (size_t)kD * kD * 2;          // +2 MB
  size_t oCTX   = oQKV   + (size_t)kRows * kQKVCols * 2; // +48 MB
  size_t total  = oCTX   + (size_t)kRows * kD * 2;       // +16 MB = ~88 MB
  if (ws_size < total) return;

  unsigned short* Xbf   = (unsigned short*)(ws + oXbf);
  unsigned short* Vtb   = (unsigned short*)(ws + oXbf);  // alias: Xbf dead after GEMM1
  unsigned short* WqkvT = (unsigned short*)(ws + oWqkvT);
  unsigned short* WpT   = (unsigned short*)(ws + oWpT);
  unsigned short* QKV   = (unsigned short*)(ws + oQKV);
  unsigned short* CTX   = (unsigned short*)(ws + oCTX);

  cvt_bf16_kernel<<<2048, 256, 0, stream>>>(x, Xbf, kRows * kD / 4);
  transpose_cvt_kernel<<<dim3(kQKVCols / 32, kD / 32), dim3(32, 8), 0, stream>>>(Wqkv, WqkvT, kD, kQKVCols);
  transpose_cvt_kernel<<<dim3(kD / 32, kD / 32), dim3(32, 8), 0, stream>>>(Wproj, WpT, kD, kD);
  gemm_bt_kernel<true><<<dim3(kQKVCols / 128, kRows / 128), 256, 0, stream>>>(
      Xbf, WqkvT, bqkv, QKV, kRows, kQKVCols, kD);
  vtrans_kernel<<<dim3(16, 128), 256, 0, stream>>>(QKV, Vtb);
  attn_kernel<<<2048, 256, 0, stream>>>(QKV, Vtb, CTX);
  gemm_bt_kernel<false><<<dim3(kD / 128, kRows / 128), 256, 0, stream>>>(
      CTX, WpT, bproj, out, kRows, kD, kD);
}

// Round 4
// 168.774 us; speedup vs baseline: 1.5699x; 1.1229x over previous
//
#include <hip/hip_runtime.h>

#define AS1(p) ((const __attribute__((address_space(1))) void*)(p))
#define AS3(p) ((__attribute__((address_space(3))) void*)(p))

typedef __attribute__((ext_vector_type(8))) short bf16x8;
typedef __attribute__((ext_vector_type(4))) float f32x4;
typedef __attribute__((ext_vector_type(16))) float f32x16;

static constexpr int kBatch = 8;
static constexpr int kSeq = 1024;
static constexpr int kD = 1024;
static constexpr int kH = 16;
static constexpr int kHD = 64;
static constexpr int kRows = kBatch * kSeq;   // 8192
static constexpr int kQKVCols = 3 * kD;       // 3072

__device__ __forceinline__ unsigned short f2bf(float f) {
  union { float f; unsigned int u; } a; a.f = f;
  unsigned int r = a.u + 0x7fffu + ((a.u >> 16) & 1u);
  return (unsigned short)(r >> 16);
}

__device__ __forceinline__ unsigned pkbf(float a, float b) {
  unsigned r;
  asm("v_cvt_pk_bf16_f32 %0, %1, %2" : "=v"(r) : "v"(a), "v"(b));
  return r;
}

// ---------------- f32 -> bf16 elementwise convert (vectorized) ----------------
__global__ void cvt_bf16_kernel(const float* __restrict__ in,
                                unsigned short* __restrict__ out, int n4) {
  int i = blockIdx.x * blockDim.x + threadIdx.x;
  int stride = gridDim.x * blockDim.x;
  for (; i < n4; i += stride) {
    float4 v = reinterpret_cast<const float4*>(in)[i];
    ushort4 o;
    o.x = f2bf(v.x); o.y = f2bf(v.y); o.z = f2bf(v.z); o.w = f2bf(v.w);
    reinterpret_cast<ushort4*>(out)[i] = o;
  }
}

// ---------------- transpose + convert: W (rows x cols) -> Wt (cols x rows) bf16
__global__ void transpose_cvt_kernel(const float* __restrict__ W,
                                     unsigned short* __restrict__ Wt,
                                     int rows, int cols) {
  __shared__ float tile[32][33];
  int c0 = blockIdx.x * 32, r0 = blockIdx.y * 32;
  int tx = threadIdx.x, ty = threadIdx.y;
#pragma unroll
  for (int i = 0; i < 32; i += 8)
    tile[ty + i][tx] = W[(size_t)(r0 + ty + i) * cols + (c0 + tx)];
  __syncthreads();
#pragma unroll
  for (int i = 0; i < 32; i += 8)
    Wt[(size_t)(c0 + ty + i) * rows + (r0 + tx)] = f2bf(tile[tx][ty + i]);
}

// ---------------- V transpose: QKV -> Vt[bh][d][n~] (bf16), n~ = bits2,3 of n
// swapped so that attn's natural P-slot order pairs with contiguous V reads.
__device__ __forceinline__ int swap23(int x) {
  return (x & ~12) | ((x & 4) << 1) | ((x & 8) >> 1);
}
__global__ __launch_bounds__(256) void vtrans_kernel(
    const unsigned short* __restrict__ qkv, unsigned short* __restrict__ Vt) {
  __shared__ alignas(16) unsigned short tile[64][72];
  const int nt = blockIdx.x, bh = blockIdx.y;
  const int b = bh >> 4, h = bh & 15;
  const unsigned short* Vb = qkv + (size_t)b * kSeq * kQKVCols + 2 * kD + h * kHD;
  const int t = threadIdx.x;
#pragma unroll
  for (int r = 0; r < 2; ++r) {
    const int c = r * 256 + t;
    const int n = c >> 3, d8 = c & 7;
    uint4 v = *reinterpret_cast<const uint4*>(Vb + (size_t)(nt * 64 + n) * kQKVCols + d8 * 8);
    *reinterpret_cast<uint4*>(&tile[n][d8 * 8]) = v;
  }
  __syncthreads();
#pragma unroll
  for (int r = 0; r < 2; ++r) {
    const int c = r * 256 + t;
    const int d = c >> 3, n8 = c & 7;
    unsigned short w8[8];
#pragma unroll
    for (int j = 0; j < 8; ++j) w8[j] = tile[swap23(n8 * 8 + j)][d];
    *reinterpret_cast<uint4*>(Vt + (size_t)bh * kHD * kSeq + (size_t)d * kSeq + nt * 64 + n8 * 8) =
        *reinterpret_cast<uint4*>(w8);
  }
}

// ---------------- bf16 GEMM: C = A(MxK) * Bt(NxK)^T + bias, 128x128 tile -----
template <bool OUT_BF16>
__global__ __launch_bounds__(256) void gemm_bt_kernel(
    const unsigned short* __restrict__ A,
    const unsigned short* __restrict__ Bt,
    const float* __restrict__ bias,
    void* __restrict__ Cout, int M, int Nn, int K) {
  constexpr int BK = 64;
  __shared__ alignas(16) unsigned short As[128 * BK];
  __shared__ alignas(16) unsigned short Bs[128 * BK];
  const int t = threadIdx.x;
  const int lane = t & 63;
  const int w = t >> 6;
  const int wr = w >> 1, wc = w & 1;
  const int l15 = lane & 15, lhi = lane >> 4;
  const int nwg = gridDim.x * gridDim.y;
  const int lin = blockIdx.y * gridDim.x + blockIdx.x;
  const int swz = (lin & 7) * (nwg >> 3) + (lin >> 3);
  const int row0 = (swz / gridDim.x) * 128;
  const int col0 = (swz % gridDim.x) * 128;

  f32x4 acc[4][4] = {};
  const int ldsb = (t & ~63) * 16;

  for (int k0 = 0; k0 < K; k0 += BK) {
    __syncthreads();
#pragma unroll
    for (int r = 0; r < 4; ++r) {
      int c = r * 256 + t;
      int arow = c >> 3;
      int ccol = ((c & 7) ^ (arow & 7)) * 8;
      const unsigned short* ga = A + (size_t)(row0 + arow) * K + (k0 + ccol);
      const unsigned short* gb = Bt + (size_t)(col0 + arow) * K + (k0 + ccol);
      char* la = (char*)As + r * 4096 + ldsb;
      char* lb = (char*)Bs + r * 4096 + ldsb;
      __builtin_amdgcn_global_load_lds(AS1(ga), AS3(la), 16, 0, 0);
      __builtin_amdgcn_global_load_lds(AS1(gb), AS3(lb), 16, 0, 0);
    }
    __syncthreads();
#pragma unroll
    for (int kk = 0; kk < 2; ++kk) {
      bf16x8 af[4], bfr[4];
#pragma unroll
      for (int mi = 0; mi < 4; ++mi) {
        int rowa = wr * 64 + mi * 16 + l15;
        int chunk = (kk * 4 + lhi) ^ (rowa & 7);
        af[mi] = *reinterpret_cast<const bf16x8*>((const char*)As + rowa * 128 + chunk * 16);
      }
#pragma unroll
      for (int ni = 0; ni < 4; ++ni) {
        int rowb = wc * 64 + ni * 16 + l15;
        int chunk = (kk * 4 + lhi) ^ (rowb & 7);
        bfr[ni] = *reinterpret_cast<const bf16x8*>((const char*)Bs + rowb * 128 + chunk * 16);
      }
#pragma unroll
      for (int mi = 0; mi < 4; ++mi)
#pragma unroll
        for (int ni = 0; ni < 4; ++ni)
          acc[mi][ni] = __builtin_amdgcn_mfma_f32_16x16x32_bf16(af[mi], bfr[ni], acc[mi][ni], 0, 0, 0);
    }
  }
#pragma unroll
  for (int mi = 0; mi < 4; ++mi) {
    int rbase = row0 + wr * 64 + mi * 16 + lhi * 4;
#pragma unroll
    for (int ni = 0; ni < 4; ++ni) {
      int col = col0 + wc * 64 + ni * 16 + l15;
      float bv = bias[col];
#pragma unroll
      for (int j = 0; j < 4; ++j) {
        float v = acc[mi][ni][j] + bv;
        if (OUT_BF16)
          ((unsigned short*)Cout)[(size_t)(rbase + j) * Nn + col] = f2bf(v);
        else
          ((float*)Cout)[(size_t)(rbase + j) * Nn + col] = v;
      }
    }
  }
}

// ---------------- fused flash attention, 32x32 MFMA, fully in-register P -----
// 4 waves/block, 32 q-rows/wave; KBLK=64; double-buffered LDS, stage-before-
// compute. S^T = K Q^T and O^T = V^T P^T so stats/rescale are lane-local for
// q = lane&31. P is packed in natural C/D order (no cross-lane); the matching
// n-permutation is pre-applied to Vt by vtrans (swap23), so PV reads stay
// contiguous b128.
__global__ __launch_bounds__(256) void attn_kernel(
    const unsigned short* __restrict__ qkv,  // 8192 x 3072 bf16 bits
    const unsigned short* __restrict__ Vt,   // [128][64][1024] bf16 bits (n-permuted)
    unsigned short* __restrict__ ctx) {      // 8192 x 1024 bf16 bits
  __shared__ alignas(16) char smem[32768];   // 2 x (K 8KB | V 8KB); epi reuses 16KB
  const int qt = blockIdx.x >> 7;            // 0..7
  const int bh = blockIdx.x & 127;
  const int b = bh >> 4, h = bh & 15;
  const int t = threadIdx.x, lane = t & 63, w = t >> 6;
  const int l31 = lane & 31, hi = lane >> 5;

  const unsigned short* Qb = qkv + (size_t)b * kSeq * kQKVCols + h * kHD;
  const unsigned short* Kb = Qb + kD;
  const unsigned short* Vtb = Vt + (size_t)bh * kHD * kSeq;

  // Q B-frags (col=q=l31, slot k covers d = s*16 + hi*8 + j), hoisted
  bf16x8 qf[4];
  const int qrow = qt * 128 + w * 32 + l31;
#pragma unroll
  for (int s = 0; s < 4; ++s)
    qf[s] = *reinterpret_cast<const bf16x8*>(Qb + (size_t)qrow * kQKVCols + s * 16 + hi * 8);

  auto stage = [&](int kt, int bufb) {
#pragma unroll
    for (int r = 0; r < 2; ++r) {
      const int c = r * 256 + t;
      const int row = c >> 3;
      const int sc = ((c & 7) ^ (row & 7)) * 8;  // pre-swizzled source (rule #21)
      const unsigned short* gk = Kb + (size_t)(kt * 64 + row) * kQKVCols + sc;
      const unsigned short* gv = Vtb + (size_t)row * kSeq + kt * 64 + sc;
      char* lk = smem + bufb + r * 4096 + (t & ~63) * 16;
      char* lv = smem + bufb + 8192 + r * 4096 + (t & ~63) * 16;
      __builtin_amdgcn_global_load_lds(AS1(gk), AS3(lk), 16, 0, 0);
      __builtin_amdgcn_global_load_lds(AS1(gv), AS3(lv), 16, 0, 0);
    }
  };

  f32x16 oacc[2] = {};
  float mrun = -3.0e38f, lrun = 0.f;
  constexpr float kSc = 0.125f * 1.44269504f;  // head-scale * log2(e)

  stage(0, 0);
  __syncthreads();
  int cur = 0;
  for (int kt = 0; kt < 16; ++kt) {
    if (kt < 15) stage(kt + 1, (cur ^ 1) * 16384);  // issue-before-compute
    const char* Kp = smem + cur * 16384;
    const char* Vp = Kp + 8192;

    // S^T = K Q^T : 8x mfma 32x32x16 (A=K rows n, B=Q cols q)
    f32x16 sacc[2] = {};
    __builtin_amdgcn_s_setprio(1);
#pragma unroll
    for (int nb = 0; nb < 2; ++nb) {
      const int n = nb * 32 + l31;
#pragma unroll
      for (int s = 0; s < 4; ++s) {
        const int ch = (s * 2 + hi) ^ (n & 7);
        bf16x8 kf = *reinterpret_cast<const bf16x8*>(Kp + n * 128 + ch * 16);
        sacc[nb] = __builtin_amdgcn_mfma_f32_32x32x16_bf16(kf, qf[s], sacc[nb], 0, 0, 0);
      }
    }
    __builtin_amdgcn_s_setprio(0);

    // online softmax for q = l31 (lane holds 32 of 64 n; partner lane^32 rest)
    float tm = sacc[0][0];
#pragma unroll
    for (int nb = 0; nb < 2; ++nb)
#pragma unroll
      for (int r = 0; r < 16; ++r) tm = fmaxf(tm, sacc[nb][r]);
    tm = fmaxf(tm, __shfl_xor(tm, 32, 64));
    const float tms = tm * kSc;
    if (!__all(tms <= mrun + 8.0f)) {  // defer-max (T13)
      const float mnew = fmaxf(mrun, tms);
      const float corr = __builtin_amdgcn_exp2f(mrun - mnew);
      mrun = mnew;
      lrun *= corr;
#pragma unroll
      for (int db = 0; db < 2; ++db)
#pragma unroll
        for (int r = 0; r < 16; ++r) oacc[db][r] *= corr;
    }
    float ps = 0.f;
#pragma unroll
    for (int nb = 0; nb < 2; ++nb)
#pragma unroll
      for (int r = 0; r < 16; ++r) {
        const float e = __builtin_amdgcn_exp2f(__builtin_fmaf(sacc[nb][r], kSc, -mrun));
        sacc[nb][r] = e;
        ps += e;
      }
    lrun += ps + __shfl_xor(ps, 32, 64);

    // pack P^T B-frags in natural C/D order (no cross-lane movement):
    // pf[s] slot (hi,j) holds n = s*16 + 8*(j>>2) + (j&3) + 4*hi — Vt's swap23
    // permutation makes V-slots carry the identical n.
    bf16x8 pf[4];
#pragma unroll
    for (int s = 0; s < 4; ++s) {
      const int nb = s >> 1, h2 = (s & 1) * 8;
      union { unsigned u[4]; bf16x8 v; } pk4;
#pragma unroll
      for (int i = 0; i < 4; ++i)
        pk4.u[i] = pkbf(sacc[nb][h2 + 2 * i], sacc[nb][h2 + 2 * i + 1]);
      pf[s] = pk4.v;
    }

    // O^T += V^T P^T : 8x mfma 32x32x16 (A=V^T rows d, B=P^T cols q)
    __builtin_amdgcn_s_setprio(1);
#pragma unroll
    for (int db = 0; db < 2; ++db) {
      const int dr = db * 32 + l31;
#pragma unroll
      for (int s = 0; s < 4; ++s) {
        const int ch = (s * 2 + hi) ^ (dr & 7);
        bf16x8 vf = *reinterpret_cast<const bf16x8*>(Vp + dr * 128 + ch * 16);
        oacc[db] = __builtin_amdgcn_mfma_f32_32x32x16_bf16(vf, pf[s], oacc[db], 0, 0, 0);
      }
    }
    __builtin_amdgcn_s_setprio(0);
    __syncthreads();  // staging drained + all waves done reading cur
    cur ^= 1;
  }

  // epilogue: O^T -> LDS (swizzled, bf16, /lrun) -> coalesced ctx stores
  const float rl = 1.0f / lrun;
  const int qlocal = w * 32 + l31;
#pragma unroll
  for (int db = 0; db < 2; ++db)
#pragma unroll
    for (int g = 0; g < 4; ++g) {
      const unsigned u0 = pkbf(oacc[db][g * 4 + 0] * rl, oacc[db][g * 4 + 1] * rl);
      const unsigned u1 = pkbf(oacc[db][g * 4 + 2] * rl, oacc[db][g * 4 + 3] * rl);
      const int ch = db * 4 + g;
      uint2 uu; uu.x = u0; uu.y = u1;
      *reinterpret_cast<uint2*>(smem + qlocal * 128 + ((ch ^ (qlocal & 7)) * 16) + hi * 8) = uu;
    }
  __syncthreads();
#pragma unroll
  for (int it = 0; it < 4; ++it) {
    const int idx = it * 256 + t;
    const int row = idx >> 3, ch = idx & 7;
    const uint4 vv = *reinterpret_cast<const uint4*>(smem + row * 128 + ((ch ^ (row & 7)) * 16));
    *reinterpret_cast<uint4*>(ctx + (size_t)(b * kSeq + qt * 128 + row) * kD + h * kHD + ch * 8) = vv;
  }
}

extern "C" void kernel_launch(void* const* d_in, const int* in_sizes, int n_in,
                              void* d_out, int out_size, void* d_ws, size_t ws_size,
                              hipStream_t stream) {
  const float* x     = (const float*)d_in[0];
  const float* Wqkv  = (const float*)d_in[1];
  const float* bqkv  = (const float*)d_in[2];
  const float* Wproj = (const float*)d_in[3];
  const float* bproj = (const float*)d_in[4];
  float* out = (float*)d_out;

  char* ws = (char*)d_ws;
  size_t oXbf   = 0;                                     // 16 MB (aliased by Vt)
  size_t oWqkvT = oXbf   + (size_t)kRows * kD * 2;
  size_t oWpT   = oWqkvT + (size_t)kQKVCols * kD * 2;
  size_t oQKV   = oWpT   + (size_t)kD * kD * 2;
  size_t oCTX   = oQKV   + (size_t)kRows * kQKVCols * 2;
  size_t total  = oCTX   + (size_t)kRows * kD * 2;
  if (ws_size < total) return;

  unsigned short* Xbf   = (unsigned short*)(ws + oXbf);
  unsigned short* Vtb   = (unsigned short*)(ws + oXbf);  // alias: Xbf dead after GEMM1
  unsigned short* WqkvT = (unsigned short*)(ws + oWqkvT);
  unsigned short* WpT   = (unsigned short*)(ws + oWpT);
  unsigned short* QKV   = (unsigned short*)(ws + oQKV);
  unsigned short* CTX   = (unsigned short*)(ws + oCTX);

  cvt_bf16_kernel<<<2048, 256, 0, stream>>>(x, Xbf, kRows * kD / 4);
  transpose_cvt_kernel<<<dim3(kQKVCols / 32, kD / 32), dim3(32, 8), 0, stream>>>(Wqkv, WqkvT, kD, kQKVCols);
  transpose_cvt_kernel<<<dim3(kD / 32, kD / 32), dim3(32, 8), 0, stream>>>(Wproj, WpT, kD, kD);
  gemm_bt_kernel<true><<<dim3(kQKVCols / 128, kRows / 128), 256, 0, stream>>>(
      Xbf, WqkvT, bqkv, QKV, kRows, kQKVCols, kD);
  vtrans_kernel<<<dim3(16, 128), 256, 0, stream>>>(QKV, Vtb);
  attn_kernel<<<1024, 256, 0, stream>>>(QKV, Vtb, CTX);
  gemm_bt_kernel<false><<<dim3(kD / 128, kRows / 128), 256, 0, stream>>>(
      CTX, WpT, bproj, out, kRows, kD, kD);
}